// Round 13
// baseline (92.481 us; speedup 1.0000x reference)
//
#include <hip/hip_runtime.h>
#include <hip/hip_bf16.h>

#define HH 8
#define DD 64
#define NN 256
#define Q1c 21
#define Q2c 21
#define MM 4096
#define KTOT 2048   // HH*NN

typedef __attribute__((ext_vector_type(4))) int i32x4;
typedef __attribute__((ext_vector_type(16))) int i32x16;

// Kernel A (fused): blocks 0..511 = Z2 byte-pack; block 512 = V quantize +
// zero Sexp/Ene/Mmat/out; blocks 513..2560 = softmax + qsfF fragment write.
// qsfF layout: byte = ((u*2+hf)*4 + (s01*2+lo))*4096 + i*16 + d*4 + b
// where j = u*16 + lo*8 + hf*4 + s01*2 + dl, d = dl*2 + (h>>2), b = h&3.
__global__ void k_combo(const int* __restrict__ Z2, unsigned char* __restrict__ Z2t,
                        const float* __restrict__ Vf, unsigned char* __restrict__ qVt,
                        float* __restrict__ sVbuf, float* __restrict__ Sexp,
                        float* __restrict__ outp,
                        const float* __restrict__ Q, const float* __restrict__ K,
                        float* __restrict__ sf, unsigned char* __restrict__ qsfF) {
  __shared__ float qs[DD];
  __shared__ float red[4];
  const int bid = blockIdx.x;
  const int t = threadIdx.x;

  if (bid < 512) {            // ---- pack Z2 -> bytes [j/8][m][8] ----
    int jb = bid >> 4;
    int m  = ((bid & 15) << 8) + t;
    unsigned lo = 0, hi = 0;
#pragma unroll
    for (int r = 0; r < 4; ++r) lo |= ((unsigned)Z2[(jb*8 + r)*MM + m] & 255u) << (8*r);
#pragma unroll
    for (int r = 0; r < 4; ++r) hi |= ((unsigned)Z2[(jb*8 + 4 + r)*MM + m] & 255u) << (8*r);
    uint2 v; v.x = lo; v.y = hi;
    *reinterpret_cast<uint2*>(Z2t + ((size_t)jb*MM + m)*8) = v;
    return;
  }
  if (bid == 512) {           // ---- quantize V + zero accumulator buffers ----
    // Sexp[4096] and Ene[4096] and Mmat[36] are contiguous from Sexp
    for (int x = t; x < 8192 + 48; x += 256) Sexp[x] = 0.f;
    if (t == 0) outp[0] = 0.f;
    float mx = 0.f;
    for (int x = t; x < HH*Q1c*Q2c; x += 256) mx = fmaxf(mx, fabsf(Vf[x]));
#pragma unroll
    for (int o = 32; o; o >>= 1) mx = fmaxf(mx, __shfl_xor(mx, o));
    if ((t & 63) == 0) red[t >> 6] = mx;
    __syncthreads();
    mx = fmaxf(fmaxf(red[0], red[1]), fmaxf(red[2], red[3]));
    if (t == 0) sVbuf[0] = mx / 127.f;
    float inv = 127.f / mx;
    for (int x = t; x < HH*Q1c*Q2c; x += 256) {
      int h = x / (Q1c*Q2c);
      int rem = x - h*(Q1c*Q2c);
      int a = rem / Q2c, c = rem - a*Q2c;
      int qv = __float2int_rn(Vf[x] * inv);
      qVt[(a*Q2c + c)*8 + h] = (unsigned char)(qv & 255);
    }
    return;
  }
  // ---- softmax (1 row per block, proven R11 form) ----
  const int bb = bid - 513;
  const int h = bb >> 8;
  const int i = bb & 255;
  const int j = t;
  if (j < DD) qs[j] = Q[(h*DD + j)*NN + i];
  __syncthreads();
  float e = 0.f;
#pragma unroll
  for (int d = 0; d < DD; ++d) e = fmaf(qs[d], K[(h*DD + d)*NN + j], e);
  float mx = e;
#pragma unroll
  for (int o = 32; o; o >>= 1) mx = fmaxf(mx, __shfl_xor(mx, o));
  if ((j & 63) == 0) red[j >> 6] = mx;
  __syncthreads();
  mx = fmaxf(fmaxf(red[0], red[1]), fmaxf(red[2], red[3]));
  float p = __expf(e - mx);
  float s = p;
#pragma unroll
  for (int o = 32; o; o >>= 1) s += __shfl_xor(s, o);
  __syncthreads();
  if ((j & 63) == 0) red[j >> 6] = s;
  __syncthreads();
  s = red[0] + red[1] + red[2] + red[3];
  p = p / s;
  sf[(h*NN + i)*NN + j] = p;
  int u = j >> 4, lo2 = (j >> 3) & 1, hf = (j >> 2) & 1, s01 = (j >> 1) & 1, dl = j & 1;
  int d = dl*2 + (h >> 2), b = h & 3;
  qsfF[(size_t)((u*2 + hf)*4 + (s01*2 + lo2))*4096 + i*16 + d*4 + b] =
      (unsigned char)__float2int_rn(p * 127.f);
}

// Kernel 3: int8 GEMM (R11 schedule: A prefetched one phase ahead; one barrier
// per 32k step) + conflict-free tbl[c][rep] + FOLDED Mmat side-task (bid<64).
// 4 waves x (64 rows x 64 cols); A from global (L2-hot); B built cooperatively
// per step into double-buffered LDS.
__global__ __launch_bounds__(256, 4) void k_gemm(
    const unsigned char* __restrict__ qsfF, const unsigned char* __restrict__ qVt,
    const float* __restrict__ sVbuf, const float* __restrict__ sf,
    float* __restrict__ Mmat,
    const int* __restrict__ Z1, const unsigned char* __restrict__ Z2t,
    float* __restrict__ Sexp, float* __restrict__ Ene) {
  __shared__ __align__(16) unsigned char Bl[2][4096];
  __shared__ int tbl[Q1c * 64];  // [c][rep]: int2 at dword c*64 + 2*rep
  __shared__ float mm[4][36];

  const int t  = threadIdx.x;
  const int bid = blockIdx.x;

  if (bid < 64) {   // ---- folded Mmat path (overlaps gemm blocks) ----
    float pr[36];
#pragma unroll
    for (int x = 0; x < 36; ++x) pr[x] = 0.f;
#pragma unroll
    for (int k = 0; k < 4; ++k) {
      int p = bid*1024 + k*256 + t;
      int i = p >> 8, j = p & 255;
      float v[HH];
#pragma unroll
      for (int h = 0; h < HH; ++h) v[h] = sf[(h*NN + i)*NN + j];
      int idx = 0;
#pragma unroll
      for (int h = 0; h < HH; ++h)
#pragma unroll
        for (int k2 = h; k2 < HH; ++k2) pr[idx++] += v[h]*v[k2];
    }
#pragma unroll
    for (int x = 0; x < 36; ++x) {
#pragma unroll
      for (int o = 32; o; o >>= 1) pr[x] += __shfl_xor(pr[x], o);
    }
    int w = t >> 6;
    if ((t & 63) == 0) {
#pragma unroll
      for (int x = 0; x < 36; ++x) mm[w][x] = pr[x];
    }
    __syncthreads();
    if (t < 36) atomicAdd(&Mmat[t], mm[0][t] + mm[1][t] + mm[2][t] + mm[3][t]);
    return;
  }

  const int w  = t >> 6;
  const int l  = t & 63;
  const int lc = l & 31;
  const int lo = l >> 5;

  // XCD swizzle over gemm blocks: gid in [0,1344)
  const int gid  = bid - 64;
  const int xcd  = gid & 7;
  const int q    = gid >> 3;        // 0..167
  const int mblk = xcd*8 + q/21;    // 0..63
  const int a_blk = q - (q/21)*21;  // 0..20
  const int m0 = mblk * 64;
  const int wrow = w * 64;

  // build-role indices (block-wide cooperative B build)
  const int bcol = t & 63;          // column within tile
  const int bkg  = (t >> 6) & 1;    // k-group (lo')
  const int bs   = t >> 7;          // s01'
  const int brep = (t & 31) << 1;   // 2*rep (dwords)
  const int boff = ((bs*2048) + bcol*32 + bkg*16) ^ ((bcol & 4) << 2);
  const unsigned char* zcolp = Z2t + (size_t)(m0 + bcol) * 8;

  // fragment-read / A offsets (per lane)
  const int roff = (lc*32 + lo*16) ^ ((lc & 4) << 2);
  const size_t aoff = (size_t)lo*4096 + (size_t)(wrow + lc)*16;

  // conflict-free tbl init: bank = 2*rep, independent of c
  for (int x = t; x < Q1c*32; x += 256) {
    int c = x >> 5, rep = x & 31;
    int2 v = *reinterpret_cast<const int2*>(qVt + (a_blk*Q2c + c)*8);
    *reinterpret_cast<int2*>(&tbl[(c << 6) + 2*rep]) = v;
  }

  i32x16 acc[2][2];
#pragma unroll
  for (int mr = 0; mr < 2; ++mr)
#pragma unroll
    for (int ct = 0; ct < 2; ++ct)
#pragma unroll
      for (int r = 0; r < 16; ++r) acc[mr][ct][r] = 0;

#define ZLDU(uu, zd)                                                           \
  {                                                                            \
    const int uc = ((uu) > 15) ? 15 : (uu);                                    \
    zd = *reinterpret_cast<const uint2*>(zcolp + ((size_t)(uc*2 + bkg)*MM)*8); \
  }

#define ALOADG(ss, Ad)                                                         \
  {                                                                            \
    const int sc = ((ss) > 31) ? 31 : (ss);                                    \
    const unsigned char* ap = qsfF + ((size_t)sc << 14) + aoff;                \
    _Pragma("unroll")                                                          \
    for (int s01 = 0; s01 < 2; ++s01)                                          \
      _Pragma("unroll")                                                        \
      for (int mr = 0; mr < 2; ++mr)                                           \
        Ad[s01][mr] = *reinterpret_cast<const i32x4*>(ap + s01*8192 + mr*512); \
  }

#define BUILD(bf, zz)                                                          \
  {                                                                            \
    const int c0 = (int)(((zz) >> (8*(bs*2  ))) & 255u);                       \
    const int c1 = (int)(((zz) >> (8*(bs*2+1))) & 255u);                       \
    int2 g0 = *reinterpret_cast<const int2*>(&tbl[(c0 << 6) + brep]);          \
    int2 g1 = *reinterpret_cast<const int2*>(&tbl[(c1 << 6) + brep]);          \
    i32x4 ch = (i32x4){g0.x, g0.y, g1.x, g1.y};                                \
    *reinterpret_cast<i32x4*>(&Bl[bf][boff]) = ch;                             \
  }

#define COMPUTE(bf, Ad)                                                        \
  {                                                                            \
    i32x4 Bf[2][2];                                                            \
    _Pragma("unroll")                                                          \
    for (int s01 = 0; s01 < 2; ++s01)                                          \
      _Pragma("unroll")                                                        \
      for (int ct = 0; ct < 2; ++ct)                                           \
        Bf[s01][ct] = *reinterpret_cast<const i32x4*>(                         \
            &Bl[bf][roff + s01*2048 + ct*1024]);                               \
    _Pragma("unroll")                                                          \
    for (int s01 = 0; s01 < 2; ++s01)                                          \
      _Pragma("unroll")                                                        \
      for (int ct = 0; ct < 2; ++ct)                                           \
        _Pragma("unroll")                                                      \
        for (int mr = 0; mr < 2; ++mr)                                         \
          acc[mr][ct] = __builtin_amdgcn_mfma_i32_32x32x32_i8(                 \
              Ad[s01][mr], Bf[s01][ct], acc[mr][ct], 0, 0, 0);                 \
  }

  uint2 ztc, ztn;
  i32x4 Aa[2][2], Ab[2][2];

  // ---- prologue ----
  ZLDU(0, ztc);
  ALOADG(0, Aa);
  __syncthreads();             // tbl visible to all waves
  BUILD(0, ztc.x);             // step (0,hf=0) -> buf0
  ZLDU(1, ztn);
  __syncthreads();             // buf0 ready

  for (int u = 0; u < 16; ++u) {
    // step (u,0): compute buf0; build (u,1)->buf1; A for next step prefetched
    ALOADG(2*u + 1, Ab);
    BUILD(1, ztc.y);
    COMPUTE(0, Aa);
    __syncthreads();
    // step (u,1): compute buf1; build (u+1,0)->buf0
    ALOADG(2*u + 2, Aa);
    BUILD(0, ztn.x);
    COMPUTE(1, Ab);
    ztc = ztn;
    ZLDU(u + 2, ztn);
    __syncthreads();
  }
#undef ZLDU
#undef ALOADG
#undef BUILD
#undef COMPUTE

  // ---- fused epilogue: dequant, exp-sum, Z1-selected sum per column m ----
  const float scale = sVbuf[0] * (1.f / 127.f);
#pragma unroll
  for (int ct = 0; ct < 2; ++ct) {
    const int m = m0 + ct*32 + lc;
    float se = 0.f, en = 0.f;
#pragma unroll
    for (int mr = 0; mr < 2; ++mr) {
#pragma unroll
      for (int r = 0; r < 16; ++r) {
        int row = wrow + mr*32 + (r & 3) + 8*(r >> 2) + 4*lo;
        float g = (float)acc[mr][ct][r] * scale;
        se += __expf(g);
        en += (Z1[row*MM + m] == a_blk) ? g : 0.f;
      }
    }
    se += __shfl_xor(se, 32);
    en += __shfl_xor(en, 32);
    if (lo == 0) {
      atomicAdd(&Sexp[m], se);
      atomicAdd(&Ene[m], en);
    }
  }
}

// Kernel 4: pl = -sum_m w[m]*(Ene[m] - log(Sexp[m] + 235)); block 16 adds reg term.
__global__ void k_final(const float* __restrict__ Sexp, const float* __restrict__ Ene,
                        const float* __restrict__ wts, const float* __restrict__ Mmat,
                        const float* __restrict__ Vf, float* __restrict__ out) {
  __shared__ float r4[4];
  float val = 0.f;
  if (blockIdx.x < 16) {
    int m = blockIdx.x * 256 + threadIdx.x;
    val = -wts[m] * (Ene[m] - logf(Sexp[m] + 235.0f));
  } else {
    int t = threadIdx.x;
    if (t < 64) {
      int h = t >> 3, k = t & 7;
      float dot = 0.f;
      for (int x = 0; x < Q1c*Q2c; ++x) dot += Vf[h*(Q1c*Q2c)+x] * Vf[k*(Q1c*Q2c)+x];
      int hh = (h < k) ? h : k;
      int kk = (h < k) ? k : h;
      int idx = hh*8 - (hh*(hh-1))/2 + (kk - hh);   // upper-tri index
      val = 0.001f * Mmat[idx] * dot;               // LAMBD = 0.001
    }
  }
#pragma unroll
  for (int o = 32; o; o >>= 1) val += __shfl_xor(val, o);
  int w = threadIdx.x >> 6;
  if ((threadIdx.x & 63) == 0) r4[w] = val;
  __syncthreads();
  if (threadIdx.x == 0) atomicAdd(out, r4[0] + r4[1] + r4[2] + r4[3]);
}

extern "C" void kernel_launch(void* const* d_in, const int* in_sizes, int n_in,
                              void* d_out, int out_size, void* d_ws, size_t ws_size,
                              hipStream_t stream) {
  const float* Q   = (const float*)d_in[0];
  const float* K   = (const float*)d_in[1];
  const float* V   = (const float*)d_in[2];
  const int*   Z1  = (const int*)d_in[3];
  const int*   Z2  = (const int*)d_in[4];
  const float* wts = (const float*)d_in[5];
  float* out = (float*)d_out;

  char* ws = (char*)d_ws;
  float*          sf   = (float*)ws;                               // 2 MB
  unsigned char*  qsfF = (unsigned char*)(ws + (2u << 20));        // 512 KB
  unsigned char*  Z2t  = (unsigned char*)(ws + (3u << 20));        // 1 MB
  float*          Sexp = (float*)(ws + (4u << 20));                // 16 KB
  float*          Ene  = (float*)(ws + (4u << 20) + (16u << 10));  // 16 KB
  float*          Mmat = (float*)(ws + (4u << 20) + (32u << 10));  // 144 B
  unsigned char*  qVt  = (unsigned char*)(ws + (4u << 20) + (40u << 10)); // 3528 B
  float*          sVbuf= (float*)(ws + (4u << 20) + (48u << 10));  // 4 B

  k_combo  <<<dim3(2561), dim3(256), 0, stream>>>(Z2, Z2t, V, qVt, sVbuf, Sexp, out, Q, K, sf, qsfF);
  k_gemm   <<<dim3(1408), dim3(256), 0, stream>>>(qsfF, qVt, sVbuf, sf, Mmat, Z1, Z2t, Sexp, Ene);
  k_final  <<<dim3(17),   dim3(256), 0, stream>>>(Sexp, Ene, wts, Mmat, V, out);
}

// Round 14
// 72.706 us; speedup vs baseline: 1.2720x; 1.2720x over previous
//
#include <hip/hip_runtime.h>
#include <hip/hip_bf16.h>

#define HH 8
#define DD 64
#define NN 256
#define Q1c 21
#define Q2c 21
#define MM 4096
#define KTOT 2048   // HH*NN

typedef __attribute__((ext_vector_type(4))) int i32x4;
typedef __attribute__((ext_vector_type(16))) int i32x16;

// Kernel A (fused): blocks 0..511 = Z2 byte-pack; block 512 = V quantize +
// VV[h][k] dot table + zero Sexp/Ene/out; blocks 513..2560 = softmax + qsfF.
// qsfF layout: byte = ((u*2+hf)*4 + (s01*2+lo))*4096 + i*16 + d*4 + b
// where j = u*16 + lo*8 + hf*4 + s01*2 + dl, d = dl*2 + (h>>2), b = h&3.
__global__ void k_combo(const int* __restrict__ Z2, unsigned char* __restrict__ Z2t,
                        const float* __restrict__ Vf, unsigned char* __restrict__ qVt,
                        float* __restrict__ sVbuf, float* __restrict__ VVg,
                        float* __restrict__ Sexp, float* __restrict__ outp,
                        const float* __restrict__ Q, const float* __restrict__ K,
                        float* __restrict__ sf, unsigned char* __restrict__ qsfF) {
  __shared__ float qs[DD];
  __shared__ float red[4];
  const int bid = blockIdx.x;
  const int t = threadIdx.x;

  if (bid < 512) {            // ---- pack Z2 -> bytes [j/8][m][8] ----
    int jb = bid >> 4;
    int m  = ((bid & 15) << 8) + t;
    unsigned lo = 0, hi = 0;
#pragma unroll
    for (int r = 0; r < 4; ++r) lo |= ((unsigned)Z2[(jb*8 + r)*MM + m] & 255u) << (8*r);
#pragma unroll
    for (int r = 0; r < 4; ++r) hi |= ((unsigned)Z2[(jb*8 + 4 + r)*MM + m] & 255u) << (8*r);
    uint2 v; v.x = lo; v.y = hi;
    *reinterpret_cast<uint2*>(Z2t + ((size_t)jb*MM + m)*8) = v;
    return;
  }
  if (bid == 512) {           // ---- quantize V, VV table, zero accumulators ----
    for (int x = t; x < 8192; x += 256) Sexp[x] = 0.f;
    if (t == 0) outp[0] = 0.f;
    // VV[h][k] upper-tri dots (36 entries), one thread each
    if (t < 36) {
      int hh = 0, rem = t;
      while (rem >= HH - hh) { rem -= HH - hh; ++hh; }
      int kk = hh + rem;
      float dot = 0.f;
      for (int x = 0; x < Q1c*Q2c; ++x)
        dot += Vf[hh*(Q1c*Q2c)+x] * Vf[kk*(Q1c*Q2c)+x];
      VVg[t] = dot;
    }
    float mx = 0.f;
    for (int x = t; x < HH*Q1c*Q2c; x += 256) mx = fmaxf(mx, fabsf(Vf[x]));
#pragma unroll
    for (int o = 32; o; o >>= 1) mx = fmaxf(mx, __shfl_xor(mx, o));
    if ((t & 63) == 0) red[t >> 6] = mx;
    __syncthreads();
    mx = fmaxf(fmaxf(red[0], red[1]), fmaxf(red[2], red[3]));
    if (t == 0) sVbuf[0] = mx / 127.f;
    float inv = 127.f / mx;
    for (int x = t; x < HH*Q1c*Q2c; x += 256) {
      int h = x / (Q1c*Q2c);
      int rem = x - h*(Q1c*Q2c);
      int a = rem / Q2c, c = rem - a*Q2c;
      int qv = __float2int_rn(Vf[x] * inv);
      qVt[(a*Q2c + c)*8 + h] = (unsigned char)(qv & 255);
    }
    return;
  }
  // ---- softmax (1 row per block, proven form) ----
  const int bb = bid - 513;
  const int h = bb >> 8;
  const int i = bb & 255;
  const int j = t;
  if (j < DD) qs[j] = Q[(h*DD + j)*NN + i];
  __syncthreads();
  float e = 0.f;
#pragma unroll
  for (int d = 0; d < DD; ++d) e = fmaf(qs[d], K[(h*DD + d)*NN + j], e);
  float mx = e;
#pragma unroll
  for (int o = 32; o; o >>= 1) mx = fmaxf(mx, __shfl_xor(mx, o));
  if ((j & 63) == 0) red[j >> 6] = mx;
  __syncthreads();
  mx = fmaxf(fmaxf(red[0], red[1]), fmaxf(red[2], red[3]));
  float p = __expf(e - mx);
  float s = p;
#pragma unroll
  for (int o = 32; o; o >>= 1) s += __shfl_xor(s, o);
  __syncthreads();
  if ((j & 63) == 0) red[j >> 6] = s;
  __syncthreads();
  s = red[0] + red[1] + red[2] + red[3];
  p = p / s;
  sf[(h*NN + i)*NN + j] = p;
  int u = j >> 4, lo2 = (j >> 3) & 1, hf = (j >> 2) & 1, s01 = (j >> 1) & 1, dl = j & 1;
  int d = dl*2 + (h >> 2), b = h & 3;
  qsfF[(size_t)((u*2 + hf)*4 + (s01*2 + lo2))*4096 + i*16 + d*4 + b] =
      (unsigned char)__float2int_rn(p * 127.f);
}

// Kernel 3: int8 GEMM (R11 schedule, conflict-free tbl[c][rep]) + register-
// LIGHT reg-term side blocks (bid >= 1344): reg = LAMBD * sum_{i,j} s^T VV s,
// one scalar accumulator per thread -> no regalloc pressure on the gemm path.
__global__ __launch_bounds__(256, 4) void k_gemm(
    const unsigned char* __restrict__ qsfF, const unsigned char* __restrict__ qVt,
    const float* __restrict__ sVbuf, const float* __restrict__ sf,
    const float* __restrict__ VVg,
    const int* __restrict__ Z1, const unsigned char* __restrict__ Z2t,
    float* __restrict__ Sexp, float* __restrict__ Ene, float* __restrict__ outp) {
  __shared__ __align__(16) unsigned char Bl[2][4096];
  __shared__ int tbl[Q1c * 64];  // [c][rep]: int2 at dword c*64 + 2*rep

  const int t  = threadIdx.x;
  const int bid = blockIdx.x;

  if (bid >= 1344) {   // ---- reg-term path: scalar accumulation only ----
    __shared__ float VVs[36];
    __shared__ float r4[4];
    if (t < 36) VVs[t] = VVg[t];
    __syncthreads();
    const int mb = bid - 1344;   // 0..63
    float accv = 0.f;
#pragma unroll
    for (int k = 0; k < 4; ++k) {
      int p = mb*1024 + k*256 + t;
      int i = p >> 8, j = p & 255;
      float v[HH];
#pragma unroll
      for (int h = 0; h < HH; ++h) v[h] = sf[(h*NN + i)*NN + j];
      int idx = 0;
#pragma unroll
      for (int h = 0; h < HH; ++h) {
        accv += v[h]*v[h]*VVs[idx++];
#pragma unroll
        for (int k2 = h + 1; k2 < HH; ++k2)
          accv += 2.f*v[h]*v[k2]*VVs[idx++];
      }
    }
#pragma unroll
    for (int o = 32; o; o >>= 1) accv += __shfl_xor(accv, o);
    if ((t & 63) == 0) r4[t >> 6] = accv;
    __syncthreads();
    if (t == 0) atomicAdd(outp, 0.001f*(r4[0] + r4[1] + r4[2] + r4[3]));
    return;
  }

  const int w  = t >> 6;
  const int l  = t & 63;
  const int lc = l & 31;
  const int lo = l >> 5;

  // XCD swizzle: xcd = bid%8 owns mblks [xcd*8, xcd*8+8) for all 21 a's.
  const int xcd  = bid & 7;
  const int q    = bid >> 3;        // 0..167
  const int mblk = xcd*8 + q/21;    // 0..63
  const int a_blk = q - (q/21)*21;  // 0..20
  const int m0 = mblk * 64;
  const int wrow = w * 64;

  // build-role indices (block-wide cooperative B build)
  const int bcol = t & 63;          // column within tile
  const int bkg  = (t >> 6) & 1;    // k-group (lo')
  const int bs   = t >> 7;          // s01'
  const int brep = (t & 31) << 1;   // 2*rep (dwords)
  const int boff = ((bs*2048) + bcol*32 + bkg*16) ^ ((bcol & 4) << 2);
  const unsigned char* zcolp = Z2t + (size_t)(m0 + bcol) * 8;

  // fragment-read / A offsets (per lane)
  const int roff = (lc*32 + lo*16) ^ ((lc & 4) << 2);
  const size_t aoff = (size_t)lo*4096 + (size_t)(wrow + lc)*16;

  // conflict-free tbl init: bank = 2*rep, independent of c
  for (int x = t; x < Q1c*32; x += 256) {
    int c = x >> 5, rep = x & 31;
    int2 v = *reinterpret_cast<const int2*>(qVt + (a_blk*Q2c + c)*8);
    *reinterpret_cast<int2*>(&tbl[(c << 6) + 2*rep]) = v;
  }

  i32x16 acc[2][2];
#pragma unroll
  for (int mr = 0; mr < 2; ++mr)
#pragma unroll
    for (int ct = 0; ct < 2; ++ct)
#pragma unroll
      for (int r = 0; r < 16; ++r) acc[mr][ct][r] = 0;

#define ZLDU(uu, zd)                                                           \
  {                                                                            \
    const int uc = ((uu) > 15) ? 15 : (uu);                                    \
    zd = *reinterpret_cast<const uint2*>(zcolp + ((size_t)(uc*2 + bkg)*MM)*8); \
  }

#define ALOADG(ss, Ad)                                                         \
  {                                                                            \
    const int sc = ((ss) > 31) ? 31 : (ss);                                    \
    const unsigned char* ap = qsfF + ((size_t)sc << 14) + aoff;                \
    _Pragma("unroll")                                                          \
    for (int s01 = 0; s01 < 2; ++s01)                                          \
      _Pragma("unroll")                                                        \
      for (int mr = 0; mr < 2; ++mr)                                           \
        Ad[s01][mr] = *reinterpret_cast<const i32x4*>(ap + s01*8192 + mr*512); \
  }

#define BUILD(bf, zz)                                                          \
  {                                                                            \
    const int c0 = (int)(((zz) >> (8*(bs*2  ))) & 255u);                       \
    const int c1 = (int)(((zz) >> (8*(bs*2+1))) & 255u);                       \
    int2 g0 = *reinterpret_cast<const int2*>(&tbl[(c0 << 6) + brep]);          \
    int2 g1 = *reinterpret_cast<const int2*>(&tbl[(c1 << 6) + brep]);          \
    i32x4 ch = (i32x4){g0.x, g0.y, g1.x, g1.y};                                \
    *reinterpret_cast<i32x4*>(&Bl[bf][boff]) = ch;                             \
  }

#define COMPUTE(bf, Ad)                                                        \
  {                                                                            \
    i32x4 Bf[2][2];                                                            \
    _Pragma("unroll")                                                          \
    for (int s01 = 0; s01 < 2; ++s01)                                          \
      _Pragma("unroll")                                                        \
      for (int ct = 0; ct < 2; ++ct)                                           \
        Bf[s01][ct] = *reinterpret_cast<const i32x4*>(                         \
            &Bl[bf][roff + s01*2048 + ct*1024]);                               \
    _Pragma("unroll")                                                          \
    for (int s01 = 0; s01 < 2; ++s01)                                          \
      _Pragma("unroll")                                                        \
      for (int ct = 0; ct < 2; ++ct)                                           \
        _Pragma("unroll")                                                      \
        for (int mr = 0; mr < 2; ++mr)                                         \
          acc[mr][ct] = __builtin_amdgcn_mfma_i32_32x32x32_i8(                 \
              Ad[s01][mr], Bf[s01][ct], acc[mr][ct], 0, 0, 0);                 \
  }

  uint2 ztc, ztn;
  i32x4 Aa[2][2], Ab[2][2];

  // ---- prologue ----
  ZLDU(0, ztc);
  ALOADG(0, Aa);
  __syncthreads();             // tbl visible to all waves
  BUILD(0, ztc.x);             // step (0,hf=0) -> buf0
  ZLDU(1, ztn);
  __syncthreads();             // buf0 ready

  for (int u = 0; u < 16; ++u) {
    // step (u,0): compute buf0; build (u,1)->buf1; A for next step prefetched
    ALOADG(2*u + 1, Ab);
    BUILD(1, ztc.y);
    COMPUTE(0, Aa);
    __syncthreads();
    // step (u,1): compute buf1; build (u+1,0)->buf0
    ALOADG(2*u + 2, Aa);
    BUILD(0, ztn.x);
    COMPUTE(1, Ab);
    ztc = ztn;
    ZLDU(u + 2, ztn);
    __syncthreads();
  }
#undef ZLDU
#undef ALOADG
#undef BUILD
#undef COMPUTE

  // ---- fused epilogue: dequant, exp-sum, Z1-selected sum per column m ----
  const float scale = sVbuf[0] * (1.f / 127.f);
#pragma unroll
  for (int ct = 0; ct < 2; ++ct) {
    const int m = m0 + ct*32 + lc;
    float se = 0.f, en = 0.f;
#pragma unroll
    for (int mr = 0; mr < 2; ++mr) {
#pragma unroll
      for (int r = 0; r < 16; ++r) {
        int row = wrow + mr*32 + (r & 3) + 8*(r >> 2) + 4*lo;
        float g = (float)acc[mr][ct][r] * scale;
        se += __expf(g);
        en += (Z1[row*MM + m] == a_blk) ? g : 0.f;
      }
    }
    se += __shfl_xor(se, 32);
    en += __shfl_xor(en, 32);
    if (lo == 0) {
      atomicAdd(&Sexp[m], se);
      atomicAdd(&Ene[m], en);
    }
  }
}

// Kernel 4: pl = -sum_m w[m]*(Ene[m] - log(Sexp[m] + 235)).
__global__ void k_final(const float* __restrict__ Sexp, const float* __restrict__ Ene,
                        const float* __restrict__ wts, float* __restrict__ out) {
  __shared__ float r4[4];
  int m = blockIdx.x * 256 + threadIdx.x;
  float val = -wts[m] * (Ene[m] - logf(Sexp[m] + 235.0f));
#pragma unroll
  for (int o = 32; o; o >>= 1) val += __shfl_xor(val, o);
  int w = threadIdx.x >> 6;
  if ((threadIdx.x & 63) == 0) r4[w] = val;
  __syncthreads();
  if (threadIdx.x == 0) atomicAdd(out, r4[0] + r4[1] + r4[2] + r4[3]);
}

extern "C" void kernel_launch(void* const* d_in, const int* in_sizes, int n_in,
                              void* d_out, int out_size, void* d_ws, size_t ws_size,
                              hipStream_t stream) {
  const float* Q   = (const float*)d_in[0];
  const float* K   = (const float*)d_in[1];
  const float* V   = (const float*)d_in[2];
  const int*   Z1  = (const int*)d_in[3];
  const int*   Z2  = (const int*)d_in[4];
  const float* wts = (const float*)d_in[5];
  float* out = (float*)d_out;

  char* ws = (char*)d_ws;
  float*          sf   = (float*)ws;                               // 2 MB
  unsigned char*  qsfF = (unsigned char*)(ws + (2u << 20));        // 512 KB
  unsigned char*  Z2t  = (unsigned char*)(ws + (3u << 20));        // 1 MB
  float*          Sexp = (float*)(ws + (4u << 20));                // 16 KB
  float*          Ene  = (float*)(ws + (4u << 20) + (16u << 10));  // 16 KB
  unsigned char*  qVt  = (unsigned char*)(ws + (4u << 20) + (40u << 10)); // 3528 B
  float*          sVbuf= (float*)(ws + (4u << 20) + (48u << 10));  // 4 B
  float*          VVg  = (float*)(ws + (4u << 20) + (52u << 10));  // 144 B

  k_combo  <<<dim3(2561), dim3(256), 0, stream>>>(Z2, Z2t, V, qVt, sVbuf, VVg, Sexp, out, Q, K, sf, qsfF);
  k_gemm   <<<dim3(1408), dim3(256), 0, stream>>>(qsfF, qVt, sVbuf, sf, VVg, Z1, Z2t, Sexp, Ene, out);
  k_final  <<<dim3(16),   dim3(256), 0, stream>>>(Sexp, Ene, wts, out);
}

// Round 15
// 71.001 us; speedup vs baseline: 1.3025x; 1.0240x over previous
//
#include <hip/hip_runtime.h>
#include <hip/hip_bf16.h>

#define HH 8
#define DD 64
#define NN 256
#define Q1c 21
#define Q2c 21
#define MM 4096
#define KTOT 2048   // HH*NN

typedef __attribute__((ext_vector_type(4))) int i32x4;
typedef __attribute__((ext_vector_type(16))) int i32x16;

// Kernel A (fused): blocks 0..511 = Z2 byte-pack; block 512 = V quantize +
// VV[h][k] dot table + zero Sexp/Ene/out; blocks 513..2560 = softmax + qsfF.
// qsfF layout: byte = ((u*2+hf)*4 + (s01*2+lo))*4096 + i*16 + d*4 + b
// where j = u*16 + lo*8 + hf*4 + s01*2 + dl, d = dl*2 + (h>>2), b = h&3.
__global__ void k_combo(const int* __restrict__ Z2, unsigned char* __restrict__ Z2t,
                        const float* __restrict__ Vf, unsigned char* __restrict__ qVt,
                        float* __restrict__ sVbuf, float* __restrict__ VVg,
                        float* __restrict__ Sexp, float* __restrict__ outp,
                        const float* __restrict__ Q, const float* __restrict__ K,
                        float* __restrict__ sf, unsigned char* __restrict__ qsfF) {
  __shared__ float qs[DD];
  __shared__ float red[4];
  const int bid = blockIdx.x;
  const int t = threadIdx.x;

  if (bid < 512) {            // ---- pack Z2 -> bytes [j/8][m][8] ----
    int jb = bid >> 4;
    int m  = ((bid & 15) << 8) + t;
    unsigned lo = 0, hi = 0;
#pragma unroll
    for (int r = 0; r < 4; ++r) lo |= ((unsigned)Z2[(jb*8 + r)*MM + m] & 255u) << (8*r);
#pragma unroll
    for (int r = 0; r < 4; ++r) hi |= ((unsigned)Z2[(jb*8 + 4 + r)*MM + m] & 255u) << (8*r);
    uint2 v; v.x = lo; v.y = hi;
    *reinterpret_cast<uint2*>(Z2t + ((size_t)jb*MM + m)*8) = v;
    return;
  }
  if (bid == 512) {           // ---- quantize V, VV table, zero accumulators ----
    for (int x = t; x < 8192; x += 256) Sexp[x] = 0.f;
    if (t == 0) outp[0] = 0.f;
    if (t < 36) {
      int hh = 0, rem = t;
      while (rem >= HH - hh) { rem -= HH - hh; ++hh; }
      int kk = hh + rem;
      float dot = 0.f;
      for (int x = 0; x < Q1c*Q2c; ++x)
        dot += Vf[hh*(Q1c*Q2c)+x] * Vf[kk*(Q1c*Q2c)+x];
      VVg[t] = dot;
    }
    float mx = 0.f;
    for (int x = t; x < HH*Q1c*Q2c; x += 256) mx = fmaxf(mx, fabsf(Vf[x]));
#pragma unroll
    for (int o = 32; o; o >>= 1) mx = fmaxf(mx, __shfl_xor(mx, o));
    if ((t & 63) == 0) red[t >> 6] = mx;
    __syncthreads();
    mx = fmaxf(fmaxf(red[0], red[1]), fmaxf(red[2], red[3]));
    if (t == 0) sVbuf[0] = mx / 127.f;
    float inv = 127.f / mx;
    for (int x = t; x < HH*Q1c*Q2c; x += 256) {
      int h = x / (Q1c*Q2c);
      int rem = x - h*(Q1c*Q2c);
      int a = rem / Q2c, c = rem - a*Q2c;
      int qv = __float2int_rn(Vf[x] * inv);
      qVt[(a*Q2c + c)*8 + h] = (unsigned char)(qv & 255);
    }
    return;
  }
  // ---- softmax (1 row per block, proven form) ----
  const int bb = bid - 513;
  const int h = bb >> 8;
  const int i = bb & 255;
  const int j = t;
  if (j < DD) qs[j] = Q[(h*DD + j)*NN + i];
  __syncthreads();
  float e = 0.f;
#pragma unroll
  for (int d = 0; d < DD; ++d) e = fmaf(qs[d], K[(h*DD + d)*NN + j], e);
  float mx = e;
#pragma unroll
  for (int o = 32; o; o >>= 1) mx = fmaxf(mx, __shfl_xor(mx, o));
  if ((j & 63) == 0) red[j >> 6] = mx;
  __syncthreads();
  mx = fmaxf(fmaxf(red[0], red[1]), fmaxf(red[2], red[3]));
  float p = __expf(e - mx);
  float s = p;
#pragma unroll
  for (int o = 32; o; o >>= 1) s += __shfl_xor(s, o);
  __syncthreads();
  if ((j & 63) == 0) red[j >> 6] = s;
  __syncthreads();
  s = red[0] + red[1] + red[2] + red[3];
  p = p / s;
  sf[(h*NN + i)*NN + j] = p;
  int u = j >> 4, lo2 = (j >> 3) & 1, hf = (j >> 2) & 1, s01 = (j >> 1) & 1, dl = j & 1;
  int d = dl*2 + (h >> 2), b = h & 3;
  qsfF[(size_t)((u*2 + hf)*4 + (s01*2 + lo2))*4096 + i*16 + d*4 + b] =
      (unsigned char)__float2int_rn(p * 127.f);
}

// Kernel 3: int8 GEMM (R14 structure) with RAW barriers in the main loop:
// s_waitcnt lgkmcnt(0) + s_barrier only -- no vmcnt(0) drain, so the A/Z
// global prefetches issued one phase ahead stay in flight across barriers
// (the barrier only needs to order LDS build/read traffic).
__global__ __launch_bounds__(256, 4) void k_gemm(
    const unsigned char* __restrict__ qsfF, const unsigned char* __restrict__ qVt,
    const float* __restrict__ sVbuf, const float* __restrict__ sf,
    const float* __restrict__ VVg,
    const int* __restrict__ Z1, const unsigned char* __restrict__ Z2t,
    float* __restrict__ Sexp, float* __restrict__ Ene, float* __restrict__ outp) {
  __shared__ __align__(16) unsigned char Bl[2][4096];
  __shared__ int tbl[Q1c * 64];  // [c][rep]: int2 at dword c*64 + 2*rep

  const int t  = threadIdx.x;
  const int bid = blockIdx.x;

  if (bid >= 1344) {   // ---- reg-term path: scalar accumulation only ----
    __shared__ float VVs[36];
    __shared__ float r4[4];
    if (t < 36) VVs[t] = VVg[t];
    __syncthreads();
    const int mb = bid - 1344;   // 0..63
    float accv = 0.f;
#pragma unroll
    for (int k = 0; k < 4; ++k) {
      int p = mb*1024 + k*256 + t;
      int i = p >> 8, j = p & 255;
      float v[HH];
#pragma unroll
      for (int h = 0; h < HH; ++h) v[h] = sf[(h*NN + i)*NN + j];
      int idx = 0;
#pragma unroll
      for (int h = 0; h < HH; ++h) {
        accv += v[h]*v[h]*VVs[idx++];
#pragma unroll
        for (int k2 = h + 1; k2 < HH; ++k2)
          accv += 2.f*v[h]*v[k2]*VVs[idx++];
      }
    }
#pragma unroll
    for (int o = 32; o; o >>= 1) accv += __shfl_xor(accv, o);
    if ((t & 63) == 0) r4[t >> 6] = accv;
    __syncthreads();
    if (t == 0) atomicAdd(outp, 0.001f*(r4[0] + r4[1] + r4[2] + r4[3]));
    return;
  }

  const int w  = t >> 6;
  const int l  = t & 63;
  const int lc = l & 31;
  const int lo = l >> 5;

  // XCD swizzle: xcd = bid%8 owns mblks [xcd*8, xcd*8+8) for all 21 a's.
  const int xcd  = bid & 7;
  const int q    = bid >> 3;        // 0..167
  const int mblk = xcd*8 + q/21;    // 0..63
  const int a_blk = q - (q/21)*21;  // 0..20
  const int m0 = mblk * 64;
  const int wrow = w * 64;

  // build-role indices (block-wide cooperative B build)
  const int bcol = t & 63;          // column within tile
  const int bkg  = (t >> 6) & 1;    // k-group (lo')
  const int bs   = t >> 7;          // s01'
  const int brep = (t & 31) << 1;   // 2*rep (dwords)
  const int boff = ((bs*2048) + bcol*32 + bkg*16) ^ ((bcol & 4) << 2);
  const unsigned char* zcolp = Z2t + (size_t)(m0 + bcol) * 8;

  // fragment-read / A offsets (per lane)
  const int roff = (lc*32 + lo*16) ^ ((lc & 4) << 2);
  const size_t aoff = (size_t)lo*4096 + (size_t)(wrow + lc)*16;

  // conflict-free tbl init: bank = 2*rep, independent of c
  for (int x = t; x < Q1c*32; x += 256) {
    int c = x >> 5, rep = x & 31;
    int2 v = *reinterpret_cast<const int2*>(qVt + (a_blk*Q2c + c)*8);
    *reinterpret_cast<int2*>(&tbl[(c << 6) + 2*rep]) = v;
  }

  i32x16 acc[2][2];
#pragma unroll
  for (int mr = 0; mr < 2; ++mr)
#pragma unroll
    for (int ct = 0; ct < 2; ++ct)
#pragma unroll
      for (int r = 0; r < 16; ++r) acc[mr][ct][r] = 0;

#define LDSBAR()                                                               \
  {                                                                            \
    asm volatile("s_waitcnt lgkmcnt(0)" ::: "memory");                         \
    __builtin_amdgcn_s_barrier();                                              \
    __builtin_amdgcn_sched_barrier(0);                                         \
  }

#define ZLDU(uu, zd)                                                           \
  {                                                                            \
    const int uc = ((uu) > 15) ? 15 : (uu);                                    \
    zd = *reinterpret_cast<const uint2*>(zcolp + ((size_t)(uc*2 + bkg)*MM)*8); \
  }

#define ALOADG(ss, Ad)                                                         \
  {                                                                            \
    const int sc = ((ss) > 31) ? 31 : (ss);                                    \
    const unsigned char* ap = qsfF + ((size_t)sc << 14) + aoff;                \
    _Pragma("unroll")                                                          \
    for (int s01 = 0; s01 < 2; ++s01)                                          \
      _Pragma("unroll")                                                        \
      for (int mr = 0; mr < 2; ++mr)                                           \
        Ad[s01][mr] = *reinterpret_cast<const i32x4*>(ap + s01*8192 + mr*512); \
  }

#define BUILD(bf, zz)                                                          \
  {                                                                            \
    const int c0 = (int)(((zz) >> (8*(bs*2  ))) & 255u);                       \
    const int c1 = (int)(((zz) >> (8*(bs*2+1))) & 255u);                       \
    int2 g0 = *reinterpret_cast<const int2*>(&tbl[(c0 << 6) + brep]);          \
    int2 g1 = *reinterpret_cast<const int2*>(&tbl[(c1 << 6) + brep]);          \
    i32x4 ch = (i32x4){g0.x, g0.y, g1.x, g1.y};                                \
    *reinterpret_cast<i32x4*>(&Bl[bf][boff]) = ch;                             \
  }

#define COMPUTE(bf, Ad)                                                        \
  {                                                                            \
    i32x4 Bf[2][2];                                                            \
    _Pragma("unroll")                                                          \
    for (int s01 = 0; s01 < 2; ++s01)                                          \
      _Pragma("unroll")                                                        \
      for (int ct = 0; ct < 2; ++ct)                                           \
        Bf[s01][ct] = *reinterpret_cast<const i32x4*>(                         \
            &Bl[bf][roff + s01*2048 + ct*1024]);                               \
    _Pragma("unroll")                                                          \
    for (int s01 = 0; s01 < 2; ++s01)                                          \
      _Pragma("unroll")                                                        \
      for (int ct = 0; ct < 2; ++ct)                                           \
        _Pragma("unroll")                                                      \
        for (int mr = 0; mr < 2; ++mr)                                         \
          acc[mr][ct] = __builtin_amdgcn_mfma_i32_32x32x32_i8(                 \
              Ad[s01][mr], Bf[s01][ct], acc[mr][ct], 0, 0, 0);                 \
  }

  uint2 ztc, ztn;
  i32x4 Aa[2][2], Ab[2][2];

  // ---- prologue ----
  ZLDU(0, ztc);
  ALOADG(0, Aa);
  LDSBAR();                    // tbl visible to all waves
  BUILD(0, ztc.x);             // step (0,hf=0) -> buf0
  ZLDU(1, ztn);
  LDSBAR();                    // buf0 ready

  for (int u = 0; u < 16; ++u) {
    // step (u,0): compute buf0; build (u,1)->buf1; A for next step prefetched
    ALOADG(2*u + 1, Ab);
    BUILD(1, ztc.y);
    COMPUTE(0, Aa);
    LDSBAR();
    // step (u,1): compute buf1; build (u+1,0)->buf0
    ALOADG(2*u + 2, Aa);
    BUILD(0, ztn.x);
    COMPUTE(1, Ab);
    ztc = ztn;
    ZLDU(u + 2, ztn);
    LDSBAR();
  }
#undef LDSBAR
#undef ZLDU
#undef ALOADG
#undef BUILD
#undef COMPUTE

  // ---- fused epilogue: dequant, exp-sum, Z1-selected sum per column m ----
  const float scale = sVbuf[0] * (1.f / 127.f);
#pragma unroll
  for (int ct = 0; ct < 2; ++ct) {
    const int m = m0 + ct*32 + lc;
    float se = 0.f, en = 0.f;
#pragma unroll
    for (int mr = 0; mr < 2; ++mr) {
#pragma unroll
      for (int r = 0; r < 16; ++r) {
        int row = wrow + mr*32 + (r & 3) + 8*(r >> 2) + 4*lo;
        float g = (float)acc[mr][ct][r] * scale;
        se += __expf(g);
        en += (Z1[row*MM + m] == a_blk) ? g : 0.f;
      }
    }
    se += __shfl_xor(se, 32);
    en += __shfl_xor(en, 32);
    if (lo == 0) {
      atomicAdd(&Sexp[m], se);
      atomicAdd(&Ene[m], en);
    }
  }
}

// Kernel 4: pl = -sum_m w[m]*(Ene[m] - log(Sexp[m] + 235)).
__global__ void k_final(const float* __restrict__ Sexp, const float* __restrict__ Ene,
                        const float* __restrict__ wts, float* __restrict__ out) {
  __shared__ float r4[4];
  int m = blockIdx.x * 256 + threadIdx.x;
  float val = -wts[m] * (Ene[m] - logf(Sexp[m] + 235.0f));
#pragma unroll
  for (int o = 32; o; o >>= 1) val += __shfl_xor(val, o);
  int w = threadIdx.x >> 6;
  if ((threadIdx.x & 63) == 0) r4[w] = val;
  __syncthreads();
  if (threadIdx.x == 0) atomicAdd(out, r4[0] + r4[1] + r4[2] + r4[3]);
}

extern "C" void kernel_launch(void* const* d_in, const int* in_sizes, int n_in,
                              void* d_out, int out_size, void* d_ws, size_t ws_size,
                              hipStream_t stream) {
  const float* Q   = (const float*)d_in[0];
  const float* K   = (const float*)d_in[1];
  const float* V   = (const float*)d_in[2];
  const int*   Z1  = (const int*)d_in[3];
  const int*   Z2  = (const int*)d_in[4];
  const float* wts = (const float*)d_in[5];
  float* out = (float*)d_out;

  char* ws = (char*)d_ws;
  float*          sf   = (float*)ws;                               // 2 MB
  unsigned char*  qsfF = (unsigned char*)(ws + (2u << 20));        // 512 KB
  unsigned char*  Z2t  = (unsigned char*)(ws + (3u << 20));        // 1 MB
  float*          Sexp = (float*)(ws + (4u << 20));                // 16 KB
  float*          Ene  = (float*)(ws + (4u << 20) + (16u << 10));  // 16 KB
  unsigned char*  qVt  = (unsigned char*)(ws + (4u << 20) + (40u << 10)); // 3528 B
  float*          sVbuf= (float*)(ws + (4u << 20) + (48u << 10));  // 4 B
  float*          VVg  = (float*)(ws + (4u << 20) + (52u << 10));  // 144 B

  k_combo  <<<dim3(2561), dim3(256), 0, stream>>>(Z2, Z2t, V, qVt, sVbuf, VVg, Sexp, out, Q, K, sf, qsfF);
  k_gemm   <<<dim3(1408), dim3(256), 0, stream>>>(qsfF, qVt, sVbuf, sf, VVg, Z1, Z2t, Sexp, Ene, out);
  k_final  <<<dim3(16),   dim3(256), 0, stream>>>(Sexp, Ene, wts, out);
}